// Round 5
// baseline (276.164 us; speedup 1.0000x reference)
//
#include <hip/hip_runtime.h>

// Problem constants (reference: BATCH=8192, IN_F=2048, OUT_F=2048)
#define M_DIM 8192
#define N_DIM 2048
#define K_DIM 2048
#define LN2F 0.69314718055994530942f
#define LOG2EF 1.44269504088896340736f
#define BIAS_PHI 0.62009741f  // softplus(1) - ln2 = log((1+e)/2)

typedef _Float16 f16x8 __attribute__((ext_vector_type(8)));
typedef float f32x4 __attribute__((ext_vector_type(4)));

// ---------------------------------------------------------------------------
// softplus(x) - ln2 via native v_exp_f32 (2^x) and v_log_f32 (log2):
//   t = x*log2e;  r = (log2(1 + 2^t) - 1) * ln2
// t >= 24: 2^t dominates -> r = x - ln2. t << 0: 2^t -> 0 -> r = -ln2 (ok).
// ---------------------------------------------------------------------------
__device__ __forceinline__ float softplus_m_ln2(float v) {
    float t = v * LOG2EF;
    float e = __builtin_amdgcn_exp2f(t);
    float r = (__builtin_amdgcn_logf(1.0f + e) - 1.0f) * LN2F;
    return t < 24.0f ? r : v - LN2F;
}

// ---------------------------------------------------------------------------
// Fused prep (UNCHANGED): blocks [0,8192) do phi; [8192,10240) do W rows.
// ---------------------------------------------------------------------------
__global__ __launch_bounds__(256) void prep_kernel(const float* __restrict__ x,
                                                   const float* __restrict__ W,
                                                   _Float16* __restrict__ phi,
                                                   _Float16* __restrict__ Wh,
                                                   float* __restrict__ bias) {
    if (blockIdx.x < 8192) {
        size_t i = ((size_t)blockIdx.x * blockDim.x + threadIdx.x) * 8;
        float4 v0 = *(const float4*)(x + i);
        float4 v1 = *(const float4*)(x + i + 4);
        union { _Float16 h[8]; uint4 u; } pk;
        pk.h[0] = (_Float16)softplus_m_ln2(v0.x);
        pk.h[1] = (_Float16)softplus_m_ln2(v0.y);
        pk.h[2] = (_Float16)softplus_m_ln2(v0.z);
        pk.h[3] = (_Float16)softplus_m_ln2(v0.w);
        pk.h[4] = (_Float16)softplus_m_ln2(v1.x);
        pk.h[5] = (_Float16)softplus_m_ln2(v1.y);
        pk.h[6] = (_Float16)softplus_m_ln2(v1.z);
        pk.h[7] = (_Float16)softplus_m_ln2(v1.w);
        *(uint4*)(phi + i) = pk.u;
    } else {
        const int o = blockIdx.x - 8192;
        const float* row = W + (size_t)o * (K_DIM + 1) + threadIdx.x * 8;
        union { _Float16 h[8]; uint4 u; } pk;
#pragma unroll
        for (int j = 0; j < 8; ++j)
            pk.h[j] = (_Float16)row[j];
        *(uint4*)(Wh + (size_t)o * K_DIM + threadIdx.x * 8) = pk.u;
        if (threadIdx.x == 0)
            bias[o] = W[(size_t)o * (K_DIM + 1) + K_DIM] * BIAS_PHI;
    }
}

// ---------------------------------------------------------------------------
// GEMM: REVERTED to R5 (best measured: 71.5 us, MfmaUtil 42-43%).
// R6-R9 (8-phase / counted-vmcnt / compiler-scheduled variants) were all
// null: 72.8-75 us. See probe_mfma_cadence below for this round's ablation.
//
// Block tile 256x128, 4 waves in 2x2 (each wave 128 rows x 64 cols),
// BK=64, acc[8][4] (128 VGPRs). LDS = 48 KB. Grid 32x16 = 512 blocks
// = exactly 2 blocks/CU.
//
// XOR swizzle (verified conflict-free): row = 64 f16 = 8 chunks of
// 16 B; physical chunk = logical chunk ^ (row & 7).
// ---------------------------------------------------------------------------
__global__ __launch_bounds__(256, 2) void kan_gemm(const _Float16* __restrict__ A,  // M x K
                                                   const _Float16* __restrict__ B,  // N x K
                                                   const float* __restrict__ bias,  // N
                                                   float* __restrict__ C) {         // M x N
    __shared__ __align__(16) _Float16 sA[256 * 64];  // 32 KB
    __shared__ __align__(16) _Float16 sB[128 * 64];  // 16 KB

    const int tid  = threadIdx.x;
    const int lane = tid & 63;
    const int wv   = tid >> 6;          // wave 0..3

    const size_t Arow0 = (size_t)blockIdx.x * 256;
    const size_t Brow0 = (size_t)blockIdx.y * 128;

    const int r8 = lane >> 3;
    const int lc = (lane & 7) ^ r8;

    const _Float16* gA = A + (Arow0 + wv * 64 + r8) * (size_t)K_DIM + lc * 8;
    _Float16* sAw = &sA[wv * 64 * 64];
    const _Float16* gB = B + (Brow0 + wv * 32 + r8) * (size_t)K_DIM + lc * 8;
    _Float16* sBw = &sB[wv * 32 * 64];

    const int wr = (wv >> 1) * 128;
    const int wc = (wv & 1) * 64;
    const int lr   = lane & 15;
    const int kph0 = ((lane >> 4) ^ (lr & 7)) * 8;

    f32x4 acc[8][4];
#pragma unroll
    for (int i = 0; i < 8; ++i)
#pragma unroll
        for (int j = 0; j < 4; ++j)
            acc[i][j] = (f32x4){0.0f, 0.0f, 0.0f, 0.0f};

    for (int k0 = 0; k0 < K_DIM; k0 += 64) {
        __syncthreads();
#pragma unroll
        for (int j = 0; j < 8; ++j)
            __builtin_amdgcn_global_load_lds(
                (const __attribute__((address_space(1))) void*)(gA + k0 + (size_t)j * 8 * K_DIM),
                (__attribute__((address_space(3))) void*)(sAw + j * 8 * 64), 16, 0, 0);
#pragma unroll
        for (int j = 0; j < 4; ++j)
            __builtin_amdgcn_global_load_lds(
                (const __attribute__((address_space(1))) void*)(gB + k0 + (size_t)j * 8 * K_DIM),
                (__attribute__((address_space(3))) void*)(sBw + j * 8 * 64), 16, 0, 0);
        __syncthreads();

#pragma unroll
        for (int kc = 0; kc < 2; ++kc) {
            const int ko = kph0 ^ (kc * 32);
            f16x8 bfr[4];
#pragma unroll
            for (int ni = 0; ni < 4; ++ni)
                bfr[ni] = *(const f16x8*)&sB[(wc + ni * 16 + lr) * 64 + ko];

#pragma unroll
            for (int mh = 0; mh < 2; ++mh) {
                f16x8 af[4];
#pragma unroll
                for (int mi = 0; mi < 4; ++mi)
                    af[mi] = *(const f16x8*)&sA[(wr + (mh * 4 + mi) * 16 + lr) * 64 + ko];
#pragma unroll
                for (int mi = 0; mi < 4; ++mi)
#pragma unroll
                    for (int ni = 0; ni < 4; ++ni)
                        acc[mh * 4 + mi][ni] = __builtin_amdgcn_mfma_f32_16x16x32_f16(
                            af[mi], bfr[ni], acc[mh * 4 + mi][ni], 0, 0, 0);
            }
        }
    }

    const int crow = (lane >> 4) * 4;
    float bsv[4];
#pragma unroll
    for (int ni = 0; ni < 4; ++ni)
        bsv[ni] = bias[Brow0 + wc + ni * 16 + lr];

#pragma unroll
    for (int mi = 0; mi < 8; ++mi) {
#pragma unroll
        for (int r = 0; r < 4; ++r) {
            float* cp = C + (Arow0 + wr + mi * 16 + crow + r) * (size_t)N_DIM
                        + Brow0 + wc + lr;
#pragma unroll
            for (int ni = 0; ni < 4; ++ni)
                cp[ni * 16] = acc[mi][ni][r] + bsv[ni];
        }
    }
}

// ---------------------------------------------------------------------------
// ABLATION PROBE (m233-style): the exact R9 8-phase cadence with ALL LDS
// reads and global_load_lds REMOVED. Same grid (32x8), 512 threads, 128 KB
// LDS (pins occupancy to 8 waves/CU = 2/SIMD), same {BAR; lgkm; setprio(1);
// 16 MFMA; setprio(0); vmcnt; BAR} skeleton. 48 iters x 8 phases x 16 MFMA
// = 96 K-tile-equivalents -> pure-MFMA floor ~99 us (guaranteed > kan_gemm
// -> visible in top-5). Frags loaded once from zeroed LDS; acc feeds a
// runtime-false guarded store (bias[] == 0 at runtime) so nothing is DCE'd
// and nothing is written.
// READ:  dur ~100-120 us => cadence fine; gap = LDS/MFMA non-overlap.
//        dur ~180-270 us => cadence/structure itself caps MFMA issue.
// ---------------------------------------------------------------------------
#define BAR   __builtin_amdgcn_s_barrier()
#define LGKM0 asm volatile("s_waitcnt lgkmcnt(0)" ::: "memory")
#define VM10  asm volatile("s_waitcnt vmcnt(10)" ::: "memory")
#define PRIO1 __builtin_amdgcn_s_setprio(1)
#define PRIO0 __builtin_amdgcn_s_setprio(0)

#define PROBE_Q(AF, BF, AI, BJ)                                                          \
    _Pragma("unroll") for (int kc = 0; kc < 2; ++kc)                                     \
    _Pragma("unroll") for (int mi = 0; mi < 4; ++mi)                                     \
    _Pragma("unroll") for (int ni = 0; ni < 2; ++ni)                                     \
        acc[(AI) + mi][(BJ) + ni] = __builtin_amdgcn_mfma_f32_16x16x32_f16(              \
            AF[mi][kc], BF[ni][kc], acc[(AI) + mi][(BJ) + ni], 0, 0, 0);

__global__ __launch_bounds__(512, 2) void probe_mfma_cadence(const float* __restrict__ bias,
                                                             float* __restrict__ sink) {
    __shared__ __align__(16) _Float16 sA[2][256 * 64];  // 64 KB
    __shared__ __align__(16) _Float16 sB[2][256 * 64];  // 64 KB

    const int tid  = threadIdx.x;
    const int lane = tid & 63;
    const int wv   = tid >> 6;
    const int wm   = wv >> 2;
    const int wn   = wv & 3;
    const int lr   = lane & 15;
    const int kph0 = ((lane >> 4) ^ (lr & 7)) * 8;

    // zero LDS (16 uint4 stores/thread), then load frags ONCE
    {
        uint4 z = {0, 0, 0, 0};
#pragma unroll
        for (int j = 0; j < 8; ++j) {
            *(uint4*)((char*)&sA[0][0] + (size_t)(tid * 8 + j) * 16) = z;
            *(uint4*)((char*)&sB[0][0] + (size_t)(tid * 8 + j) * 16) = z;
        }
    }
    __syncthreads();

    f16x8 afr0[4][2], afr1[4][2];
    f16x8 bfr0[2][2], bfr1[2][2];
#pragma unroll
    for (int kc = 0; kc < 2; ++kc) {
#pragma unroll
        for (int mi = 0; mi < 4; ++mi) {
            afr0[mi][kc] = *(const f16x8*)&sA[0][(wm * 128 + mi * 16 + lr) * 64 + (kph0 ^ (kc * 32))];
            afr1[mi][kc] = *(const f16x8*)&sA[1][(wm * 128 + 64 + mi * 16 + lr) * 64 + (kph0 ^ (kc * 32))];
        }
#pragma unroll
        for (int ni = 0; ni < 2; ++ni) {
            bfr0[ni][kc] = *(const f16x8*)&sB[0][(wn * 64 + ni * 16 + lr) * 64 + (kph0 ^ (kc * 32))];
            bfr1[ni][kc] = *(const f16x8*)&sB[1][(wn * 64 + 32 + ni * 16 + lr) * 64 + (kph0 ^ (kc * 32))];
        }
    }
    __syncthreads();

    f32x4 acc[8][4];
#pragma unroll
    for (int i = 0; i < 8; ++i)
#pragma unroll
        for (int j = 0; j < 4; ++j)
            acc[i][j] = (f32x4){0.0f, 0.0f, 0.0f, 0.0f};

    // 48 iters x 8 phases: exact R9 barrier/setprio/wait cadence, MFMA only.
    for (int it = 0; it < 48; ++it) {
        // ph0..ph3 (K-tile "even")
        BAR; LGKM0; PRIO1; PROBE_Q(afr0, bfr0, 0, 0); PRIO0; VM10; BAR;
        BAR; LGKM0; PRIO1; PROBE_Q(afr1, bfr0, 4, 0); PRIO0; VM10; BAR;
        BAR; LGKM0; PRIO1; PROBE_Q(afr1, bfr1, 4, 2); PRIO0; BAR;
        BAR;        PRIO1; PROBE_Q(afr0, bfr1, 0, 2); PRIO0; VM10; BAR;
        // ph4..ph7 (K-tile "odd")
        BAR; LGKM0; PRIO1; PROBE_Q(afr0, bfr0, 0, 0); PRIO0; VM10; BAR;
        BAR; LGKM0; PRIO1; PROBE_Q(afr1, bfr0, 4, 0); PRIO0; VM10; BAR;
        BAR; LGKM0; PRIO1; PROBE_Q(afr1, bfr1, 4, 2); PRIO0; BAR;
        BAR;        PRIO1; PROBE_Q(afr0, bfr1, 0, 2); PRIO0; VM10; BAR;
    }

    // Runtime-false guard (bias[] is all zeros): keeps acc live, never runs.
    if (bias[tid & 1023] != 0.0f) {
#pragma unroll
        for (int i = 0; i < 8; ++i)
#pragma unroll
            for (int j = 0; j < 4; ++j)
#pragma unroll
                for (int r = 0; r < 4; ++r)
                    sink[(size_t)(blockIdx.x * 8 + blockIdx.y) * 4096 + tid * 8 + i * 4 + j + r] =
                        acc[i][j][r];
    }
}

// ---------------------------------------------------------------------------
extern "C" void kernel_launch(void* const* d_in, const int* in_sizes, int n_in,
                              void* d_out, int out_size, void* d_ws, size_t ws_size,
                              hipStream_t stream) {
    const float* x = (const float*)d_in[0];   // (8192, 2048) fp32
    const float* W = (const float*)d_in[1];   // (2048, 2049) fp32
    float* out = (float*)d_out;               // (8192, 2048) fp32

    // workspace layout: phi (M*K f16) | Wh (N*K f16) | bias (N f32)  ~42 MB
    char* ws = (char*)d_ws;
    _Float16* phi = (_Float16*)ws;
    _Float16* Wh  = (_Float16*)(ws + (size_t)M_DIM * K_DIM * sizeof(_Float16));
    float* bias   = (float*)(ws + (size_t)M_DIM * K_DIM * sizeof(_Float16)
                                + (size_t)N_DIM * K_DIM * sizeof(_Float16));

    prep_kernel<<<8192 + 2048, 256, 0, stream>>>(x, W, phi, Wh, bias);
    dim3 grid(M_DIM / 256, N_DIM / 128);  // 32 x 16 = 512 blocks, 2/CU
    kan_gemm<<<grid, 256, 0, stream>>>(phi, Wh, bias, out);
    // Ablation probe (writes nothing at runtime; ~100-270 us, read from top-5)
    dim3 pgrid(32, 8);
    probe_mfma_cadence<<<pgrid, 512, 0, stream>>>(bias, (float*)ws);
}